// Round 4
// baseline (193.785 us; speedup 1.0000x reference)
//
#include <hip/hip_runtime.h>
#include <hip/hip_bf16.h>

// QFD loss: out = 0.1 * sum_b diff_b^T A diff_b, A_ij = 1 - |i-j|/85.
// Identity: q = S^2 - (2/85) * (S*sumL - sumL2), where
//   L_k = prefix sums of d, sumL = sum_{k<84} L_k, sumL2 = sum_{k<84} L_k^2.
//
// R4: R3 was 65 us vs ~20 us floor with ALL pipes idle; residual time
// invariant across occupancy changes -> fingered the 84-deep dependent
// ds_read scan chain (1 wave in 4 active) + 36-VGPR reg cap serializing
// staging. Fix: (a) 4-way segmented scan, one segment per quad lane,
// full unroll (21 independent LDS reads in flight), quad-combine via
// shuffles; (b) drop min-waves bound so staging batch stays in registers.

#define QFD_D 85
#define ROWS_PER_BLOCK 64
#define THREADS 256

__global__ __launch_bounds__(THREADS) void qfd_kernel(
    const float* __restrict__ in, const float* __restrict__ tgt,
    float* __restrict__ partial) {
    // 64 rows * 85 floats * 4 B = 21,760 B of LDS -> up to 7 blocks/CU
    __shared__ float diff[ROWS_PER_BLOCK * QFD_D];
    __shared__ float wsum[THREADS / 64];

    const int tid = threadIdx.x;
    const int E = ROWS_PER_BLOCK * QFD_D;      // 5440 floats per block
    const int base = blockIdx.x * E;           // max ~22.3M -> fits int32

    // ---- Stage |in - tgt| into LDS. 1360 float4s = 5*256 + 80.
    // All 10 global loads batched into registers before any LDS write. ----
    const float4* in4 = reinterpret_cast<const float4*>(in + base);
    const float4* tg4 = reinterpret_cast<const float4*>(tgt + base);
    float4* df4 = reinterpret_cast<float4*>(diff);

    float4 a[5], b[5];
    #pragma unroll
    for (int j = 0; j < 5; ++j) {
        a[j] = in4[tid + j * THREADS];
        b[j] = tg4[tid + j * THREADS];
    }
    float4 at, bt;
    if (tid < 80) {  // tail: float4s 1280..1359
        at = in4[1280 + tid];
        bt = tg4[1280 + tid];
    }
    #pragma unroll
    for (int j = 0; j < 5; ++j) {
        float4 r;
        r.x = fabsf(a[j].x - b[j].x);
        r.y = fabsf(a[j].y - b[j].y);
        r.z = fabsf(a[j].z - b[j].z);
        r.w = fabsf(a[j].w - b[j].w);
        df4[tid + j * THREADS] = r;
    }
    if (tid < 80) {
        float4 r;
        r.x = fabsf(at.x - bt.x);
        r.y = fabsf(at.y - bt.y);
        r.z = fabsf(at.z - bt.z);
        r.w = fabsf(at.w - bt.w);
        df4[1280 + tid] = r;
    }
    __syncthreads();

    // ---- Segmented per-row scan: thread = 4*row + q, segment q of row.
    // Segments: q0=[0,22) len 22, q1=[22,43), q2=[43,64), q3=[64,85) len 21.
    // Local: l = running prefix, a1 = sum(l), b2 = sum(l^2). ----
    const int q   = tid & 3;
    const int row = tid >> 2;                  // 0..63
    const int off = 21 * q + (q != 0);         // 0,22,43,64
    const float* dp = &diff[row * QFD_D + off];

    float l = 0.0f, a1 = 0.0f, b2 = 0.0f;
    #pragma unroll
    for (int j = 0; j < 21; ++j) {             // 21 independent LDS reads
        float v = dp[j];
        l += v;
        a1 += l;
        b2 = fmaf(l, l, b2);
    }
    if (q == 0) {                              // segment 0 has 22 elements
        float v = dp[21];
        l += v;
        a1 += l;
        b2 = fmaf(l, l, b2);
    }

    // ---- Quad combine via shuffles. P_q = exclusive prefix of seg sums.
    // sumL' (all 85 prefixes) = sum_q len_q*P_q + a_q
    // sumL2' = sum_q len_q*P_q^2 + 2*P_q*a_q + b_q
    // then sumL = sumL' - S, sumL2 = sumL2' - S^2. ----
    const int lane = tid & 63;
    const int qb   = lane & 60;                // quad base lane in wave
    float s0 = __shfl(l, qb + 0, 64);
    float s1 = __shfl(l, qb + 1, 64);
    float s2 = __shfl(l, qb + 2, 64);
    float s3 = __shfl(l, qb + 3, 64);
    float S  = (s0 + s1) + (s2 + s3);
    float P  = (q > 0 ? s0 : 0.0f) + (q > 1 ? s1 : 0.0f) + (q > 2 ? s2 : 0.0f);
    float len = (q == 0) ? 22.0f : 21.0f;
    float c1 = fmaf(len, P, a1);
    float c2 = fmaf(len * P, P, fmaf(2.0f * P, a1, b2));
    float c1s = __shfl(c1, qb + 0, 64) + __shfl(c1, qb + 1, 64)
              + __shfl(c1, qb + 2, 64) + __shfl(c1, qb + 3, 64);
    float c2s = __shfl(c2, qb + 0, 64) + __shfl(c2, qb + 1, 64)
              + __shfl(c2, qb + 2, 64) + __shfl(c2, qb + 3, 64);
    float sumL  = c1s - S;
    float sumL2 = c2s - S * S;
    float qrow  = fmaf(S, S, -(2.0f / 85.0f) * (S * sumL - sumL2));
    float val   = (q == 0) ? qrow : 0.0f;

    // ---- Block reduction -> one plain store per block (no atomics) ----
    #pragma unroll
    for (int m = 32; m > 0; m >>= 1)
        val += __shfl_xor(val, m, 64);
    if (lane == 0) wsum[tid >> 6] = val;
    __syncthreads();
    if (tid == 0) {
        float s = 0.0f;
        #pragma unroll
        for (int w = 0; w < THREADS / 64; ++w) s += wsum[w];
        partial[blockIdx.x] = s;
    }
}

// Stage 2: reduce n partials (n = 4096), write 0.1 * sum. One block.
__global__ __launch_bounds__(THREADS) void qfd_reduce_kernel(
    const float* __restrict__ partial, float* __restrict__ out, int n) {
    __shared__ float wsum[THREADS / 64];
    const int tid = threadIdx.x;
    float s = 0.0f;
    for (int i = tid; i < n; i += THREADS) s += partial[i];
    #pragma unroll
    for (int m = 32; m > 0; m >>= 1)
        s += __shfl_xor(s, m, 64);
    if ((tid & 63) == 0) wsum[tid >> 6] = s;
    __syncthreads();
    if (tid == 0) {
        float t = 0.0f;
        #pragma unroll
        for (int w = 0; w < THREADS / 64; ++w) t += wsum[w];
        out[0] = 0.1f * t;
    }
}

extern "C" void kernel_launch(void* const* d_in, const int* in_sizes, int n_in,
                              void* d_out, int out_size, void* d_ws, size_t ws_size,
                              hipStream_t stream) {
    const float* in  = (const float*)d_in[0];
    const float* tgt = (const float*)d_in[1];
    float* out = (float*)d_out;
    float* partial = (float*)d_ws;             // 4096 floats = 16 KB scratch

    const int B = in_sizes[0] / QFD_D;         // 262144
    const int grid = B / ROWS_PER_BLOCK;       // 4096 blocks

    qfd_kernel<<<grid, THREADS, 0, stream>>>(in, tgt, partial);
    qfd_reduce_kernel<<<1, THREADS, 0, stream>>>(partial, out, grid);
}

// Round 5
// 192.712 us; speedup vs baseline: 1.0056x; 1.0056x over previous
//
#include <hip/hip_runtime.h>
#include <hip/hip_bf16.h>

// QFD loss: out = 0.1 * sum_b diff_b^T A diff_b, A_ij = 1 - |i-j|/85.
// Identity: q = S^2 - (2/85) * (S*sumL - sumL2), where
//   L_k = prefix sums of d, sumL = sum_{k<84} L_k, sumL2 = sum_{k<84} L_k^2.
//
// R5: R0-R4 invariant ~65 us with all pipes idle + VGPR=36 (compiler
// serialized every "batched" staging variant -> ~2-4 loads in flight/wave,
// 2.7 TB/s effective = latency-starved). Fix: global_load_lds width=16
// (direct HBM->LDS DMA, no dest VGPRs, cannot be serialized by regalloc);
// stage RAW in+tgt (45 KB LDS), compute |in-tgt| during the segmented scan.

#define QFD_D 85
#define ROWS_PER_BLOCK 64
#define THREADS 256

// Per block: 64 rows * 85 = 5440 floats = 1360 float4s per input array.
// 22 wave-rounds of 64 float4s = 1408 slots (tail 1360..1407 = clamped junk).
#define F4_VALID 1360
#define ROUNDS 22

typedef __attribute__((address_space(1))) const void glob_cv;
typedef __attribute__((address_space(3))) void lds_v;

__global__ __launch_bounds__(THREADS) void qfd_kernel(
    const float* __restrict__ in, const float* __restrict__ tgt,
    float* __restrict__ partial) {
    __shared__ float lin[ROUNDS * 256];   // 5632 floats = 22528 B
    __shared__ float ltg[ROUNDS * 256];
    __shared__ float wsum[THREADS / 64];

    const int tid  = threadIdx.x;
    const int lane = tid & 63;
    const int wave = tid >> 6;
    const int base4 = blockIdx.x * F4_VALID;   // float4 index; max ~5.57M

    const float4* in4 = reinterpret_cast<const float4*>(in) + base4;
    const float4* tg4 = reinterpret_cast<const float4*>(tgt) + base4;

    // ---- Async DMA staging: each wave issues ~11 global_load_lds_dwordx4
    // (zero dest VGPRs -> all in flight; ~22 KB outstanding per wave).
    // LDS dest per call = wave-uniform base + lane*16. ----
    for (int r = wave; r < ROUNDS; r += 4) {
        int idx = r * 64 + lane;
        int g = idx < F4_VALID ? idx : 0;      // clamp tail (junk, never read)
        __builtin_amdgcn_global_load_lds(
            (glob_cv*)(in4 + g), (lds_v*)&lin[r * 256], 16, 0, 0);
        __builtin_amdgcn_global_load_lds(
            (glob_cv*)(tg4 + g), (lds_v*)&ltg[r * 256], 16, 0, 0);
    }
    __syncthreads();   // compiler emits vmcnt(0) drain before barrier

    // ---- Segmented per-row scan: thread = 4*row + q, segment q of row.
    // Segments: q0=[0,22) len 22, q1=[22,43), q2=[43,64), q3=[64,85) len 21.
    // diff computed on the fly from the two staged arrays. ----
    const int q   = tid & 3;
    const int row = tid >> 2;                  // 0..63
    const int off = 21 * q + (q != 0);         // 0,22,43,64
    const int p   = row * QFD_D + off;

    float l = 0.0f, a1 = 0.0f, b2 = 0.0f;
    #pragma unroll
    for (int j = 0; j < 21; ++j) {
        float v = fabsf(lin[p + j] - ltg[p + j]);
        l += v;
        a1 += l;
        b2 = fmaf(l, l, b2);
    }
    if (q == 0) {                              // segment 0 has 22 elements
        float v = fabsf(lin[p + 21] - ltg[p + 21]);
        l += v;
        a1 += l;
        b2 = fmaf(l, l, b2);
    }

    // ---- Quad combine via shuffles. P = exclusive prefix of seg sums.
    // sumL' = sum_q len_q*P_q + a_q ; sumL2' = sum_q len_q*P_q^2+2P_q a_q+b_q
    // sumL = sumL' - S ; sumL2 = sumL2' - S^2 (drop the L_84 terms). ----
    const int qb = lane & 60;
    float s0 = __shfl(l, qb + 0, 64);
    float s1 = __shfl(l, qb + 1, 64);
    float s2 = __shfl(l, qb + 2, 64);
    float s3 = __shfl(l, qb + 3, 64);
    float S  = (s0 + s1) + (s2 + s3);
    float P  = (q > 0 ? s0 : 0.0f) + (q > 1 ? s1 : 0.0f) + (q > 2 ? s2 : 0.0f);
    float len = (q == 0) ? 22.0f : 21.0f;
    float c1 = fmaf(len, P, a1);
    float c2 = fmaf(len * P, P, fmaf(2.0f * P, a1, b2));
    float c1s = __shfl(c1, qb + 0, 64) + __shfl(c1, qb + 1, 64)
              + __shfl(c1, qb + 2, 64) + __shfl(c1, qb + 3, 64);
    float c2s = __shfl(c2, qb + 0, 64) + __shfl(c2, qb + 1, 64)
              + __shfl(c2, qb + 2, 64) + __shfl(c2, qb + 3, 64);
    float sumL  = c1s - S;
    float sumL2 = c2s - S * S;
    float qrow  = fmaf(S, S, -(2.0f / 85.0f) * (S * sumL - sumL2));
    float val   = (q == 0) ? qrow : 0.0f;

    // ---- Block reduction -> one plain store per block (no atomics) ----
    #pragma unroll
    for (int m = 32; m > 0; m >>= 1)
        val += __shfl_xor(val, m, 64);
    if (lane == 0) wsum[wave] = val;
    __syncthreads();
    if (tid == 0) {
        float s = 0.0f;
        #pragma unroll
        for (int w = 0; w < THREADS / 64; ++w) s += wsum[w];
        partial[blockIdx.x] = s;
    }
}

// Stage 2: reduce n partials (n = 4096), write 0.1 * sum. One block.
__global__ __launch_bounds__(THREADS) void qfd_reduce_kernel(
    const float* __restrict__ partial, float* __restrict__ out, int n) {
    __shared__ float wsum[THREADS / 64];
    const int tid = threadIdx.x;
    float s = 0.0f;
    for (int i = tid; i < n; i += THREADS) s += partial[i];
    #pragma unroll
    for (int m = 32; m > 0; m >>= 1)
        s += __shfl_xor(s, m, 64);
    if ((tid & 63) == 0) wsum[tid >> 6] = s;
    __syncthreads();
    if (tid == 0) {
        float t = 0.0f;
        #pragma unroll
        for (int w = 0; w < THREADS / 64; ++w) t += wsum[w];
        out[0] = 0.1f * t;
    }
}

extern "C" void kernel_launch(void* const* d_in, const int* in_sizes, int n_in,
                              void* d_out, int out_size, void* d_ws, size_t ws_size,
                              hipStream_t stream) {
    const float* in  = (const float*)d_in[0];
    const float* tgt = (const float*)d_in[1];
    float* out = (float*)d_out;
    float* partial = (float*)d_ws;             // 4096 floats = 16 KB scratch

    const int B = in_sizes[0] / QFD_D;         // 262144
    const int grid = B / ROWS_PER_BLOCK;       // 4096 blocks

    qfd_kernel<<<grid, THREADS, 0, stream>>>(in, tgt, partial);
    qfd_reduce_kernel<<<1, THREADS, 0, stream>>>(partial, out, grid);
}